// Round 22
// baseline (153.973 us; speedup 1.0000x reference)
//
#include <hip/hip_runtime.h>

// Problem constants
#define NBANDS 8
#define BS 32
#define MTF 41
#define IMG 552
#define CONV 512
#define QOUT 481
#define NIMG 32
#define NN 1024.0f
#define KXP 42            // Atab kx entries per band (41 real + 1 zero pad)

// Transposed fp16 input T: [NIMG][TX][TY], zero-padded
#define TX 560
#define TY 576

#define TRB (NIMG * 81)   // transpose blocks: 2592
#define ATB 168           // atab blocks (2 entries each): 336 entries

typedef _Float16 half8 __attribute__((ext_vector_type(8)));
typedef _Float16 half2v __attribute__((ext_vector_type(2)));
typedef float f32x4 __attribute__((ext_vector_type(4)));

// ---------- prep: transpose + fp16 convert, with atab fused as extra blocks ----------
__global__ __launch_bounds__(256) void prep_fused(
    const float* __restrict__ in, _Float16* __restrict__ T,
    const float* __restrict__ w, _Float16* __restrict__ A)
{
    int bid = blockIdx.x;
    if (bid >= TRB) {
        // ---- atab role: 2 (band,kx) entries per block, 128 threads each ----
        int e = (bid - TRB) * 2 + (threadIdx.x >> 7);   // entry = band*KXP + kx
        int band = e / KXP, kx = e % KXP;
        int tt = threadIdx.x & 127;
        int s = tt >> 6, lane = tt & 63;
        int i = lane & 15;
        int kb = 32 * s + ((lane >> 4) << 3);
        const float* wp = w + band * MTF * MTF;
        half8 v;
#pragma unroll
        for (int j = 0; j < 8; ++j) {
            int ky = kb + j - i;
            v[j] = (kx < MTF && ky >= 0 && ky < MTF) ? (_Float16)wp[ky * MTF + kx]
                                                     : (_Float16)0.f;
        }
        *(half8*)&A[(((size_t)(e * 2 + s)) << 9) + lane * 8] = v;
        return;
    }

    // ---- transpose role ----
    __shared__ _Float16 s[64][74];   // pitch 74 halfs = 37 dwords, gcd(37,32)=1
    int img = bid / 81;              // 9x9 tiles of 64
    int t = bid % 81;
    int ty = t / 9, tx2 = t % 9;
    int y0 = ty * 64, x0 = tx2 * 64;
    const float* ip = in + (size_t)img * IMG * IMG;

    if (x0 + 63 < IMG) {
#pragma unroll
        for (int k = 0; k < 4; ++k) {
            int i = k * 256 + threadIdx.x;
            int r = i >> 4, c4 = i & 15;
            int y = y0 + r;
            float4 v = make_float4(0.f, 0.f, 0.f, 0.f);
            if (y < IMG) v = *(const float4*)(ip + (size_t)y * IMG + x0 + c4 * 4);
            s[c4 * 4 + 0][r] = (_Float16)v.x;
            s[c4 * 4 + 1][r] = (_Float16)v.y;
            s[c4 * 4 + 2][r] = (_Float16)v.z;
            s[c4 * 4 + 3][r] = (_Float16)v.w;
        }
    } else {
#pragma unroll
        for (int k = 0; k < 16; ++k) {
            int i = k * 256 + threadIdx.x;
            int r = i >> 6, c = i & 63;
            int y = y0 + r, x = x0 + c;
            float v = (y < IMG && x < IMG) ? ip[(size_t)y * IMG + x] : 0.f;
            s[c][r] = (_Float16)v;
        }
    }
    __syncthreads();
    _Float16* Tp = T + (size_t)img * TX * TY;
    for (int k = 0; k < 2; ++k) {
        int i = k * 256 + threadIdx.x;  // 512 = 64 xi * 8 g
        int xi = i >> 3, g = i & 7;
        int x = x0 + xi;
        if (x < TX) {
            half8 v = *(const half8*)&s[xi][g * 8];
            *(half8*)&Tp[(size_t)x * TY + y0 + g * 8] = v;
        }
    }
}

// ---------- Kernel A: 16x16x32 MFMA conv, wave = 128y x 16x, frag-sharing ----------
#define XP5 105
#define UGS (2 * XP5 * 16)    // byte stride between u-steps: 3360

__global__ __launch_bounds__(256, 4) void conv_mfma16(
    const _Float16* __restrict__ T, const _Float16* __restrict__ Atab,
    float* __restrict__ out)
{
    __shared__ __align__(16) _Float16 sB[22 * XP5 * 8];   // 36960 B
    int bid = blockIdx.x;
    int img = bid >> 5;
    int rr  = bid & 31;
    int y0 = (rr >> 3) << 7;       // 0..384
    int x0 = (rr & 7) << 6;        // 0..448
    int band = img & 7;
    int tid = threadIdx.x;

    const _Float16* Tp = T + (size_t)img * TX * TY;
    for (int e = tid; e < 22 * 104; e += 256) {
        int g = e / 104, x = e - g * 104;
        half8 v = *(const half8*)&Tp[(size_t)(x0 + x) * TY + y0 + g * 8];
        *(half8*)&sB[(size_t)(g * XP5 + x) * 8] = v;
    }
    __syncthreads();

    int l  = tid & 63;
    int wx = tid >> 6;             // 0..3 (16-col x sub-tile)
    int g4 = l >> 4;               // k-quarter -> y-group offset
    int ln = l & 15;

    const half8* Ab = (const half8*)Atab + (size_t)band * KXP * 2 * 64 + l;
    const char* bbase = (const char*)sB + ((size_t)(g4 * XP5 + (wx << 4) + ln) << 4);

    f32x4 acc[8] = {};             // 8 independent MFMA chains

    auto LDA = [&](half8 (&A)[2], int kx) {
        A[0] = Ab[(size_t)(kx * 2) * 64];
        A[1] = Ab[(size_t)(kx * 2 + 1) * 64];
    };
    auto LDB = [&](half8 (&B)[10], int kx) {
        const char* q = bbase + ((size_t)kx << 4);
#pragma unroll
        for (int i = 0; i < 10; ++i) B[i] = *(const half8*)(q + i * UGS);
    };
    auto FMAS = [&](half8 (&A)[2], half8 (&B)[10]) {
#pragma unroll
        for (int t = 0; t < 8; ++t)
            acc[t] = __builtin_amdgcn_mfma_f32_16x16x32_f16(A[0], B[t], acc[t], 0, 0, 0);
#pragma unroll
        for (int t = 0; t < 8; ++t)
            acc[t] = __builtin_amdgcn_mfma_f32_16x16x32_f16(A[1], B[t + 2], acc[t], 0, 0, 0);
    };

    half8 A0[2], A1[2], B[10];
    LDA(A0, 0);
#pragma unroll 1
    for (int kx = 0; kx < 40; kx += 2) {
        LDB(B, kx);
        LDA(A1, kx + 1);
        FMAS(A0, B);
        LDB(B, kx + 1);
        LDA(A0, kx + 2);           // <= 41 (zero-padded entry)
        FMAS(A1, B);
    }
    LDB(B, 40);
    FMAS(A0, B);

    // C/D layout (16x16): col = l&15, row = (l>>4)*4 + r
    float* op = out + (size_t)img * CONV * CONV;
    int col = x0 + (wx << 4) + ln;
    int rb  = y0 + (g4 << 2);
#pragma unroll
    for (int t = 0; t < 8; ++t) {
#pragma unroll
        for (int r = 0; r < 4; ++r)
            op[(size_t)(rb + 16 * t + r) * CONV + col] = acc[t][r];
    }
}

// ---------------- Kernel B: box-sums + Q, 31-row strips, 32 waves/CU ----------------
template<int C, int RM, int BM, bool BC>
__device__ __forceinline__ int dppadd_h2(int v) {
    int t = __builtin_amdgcn_update_dpp(0, v, C, RM, BM, BC);
    half2v a = __builtin_bit_cast(half2v, v);
    half2v b = __builtin_bit_cast(half2v, t);
    return __builtin_bit_cast(int, a + b);
}

__device__ __forceinline__ int wave_iscan_h2(int v) {
    v = dppadd_h2<0x111, 0xf, 0xf, true >(v);   // row_shr:1
    v = dppadd_h2<0x112, 0xf, 0xf, true >(v);   // row_shr:2
    v = dppadd_h2<0x114, 0xf, 0xf, true >(v);   // row_shr:4
    v = dppadd_h2<0x118, 0xf, 0xf, true >(v);   // row_shr:8
    v = dppadd_h2<0x142, 0xa, 0xf, false>(v);   // row_bcast:15 -> rows 1,3
    v = dppadd_h2<0x143, 0xc, 0xf, false>(v);   // row_bcast:31 -> rows 2,3
    return v;
}

__device__ __forceinline__ void win32pair(float sa, float sb, int lane,
                                          float& wa, float& wb) {
    half2v p = __builtin_bit_cast(half2v, __builtin_amdgcn_cvt_pkrtz(sa, sb));
    int P = wave_iscan_h2(__builtin_bit_cast(int, p));
    int Pg = __shfl(P, lane + 31, 64);
    half2v w = __builtin_bit_cast(half2v, Pg) - __builtin_bit_cast(half2v, P) + p;
    wa = (float)w[0];
    wb = (float)w[1];
}

__device__ __forceinline__ float qval(float A0, float A1, float A2, float A3) {
    float mul = A0 * A1;
    float sq  = fmaf(A0, A0, A1 * A1);
    float num = 4.f * fmaf(NN, A3, -mul) * mul;
    float dt  = fmaf(NN, A2, -sq);
    float den = dt * sq;
    bool  c1  = (dt == 0.f) && (sq != 0.f);
    float nn = num, dd = den;
    if (den == 0.f) { nn = c1 ? 2.f * mul : 1.f; dd = c1 ? sq : 1.f; }
    return nn * __builtin_amdgcn_rcpf(dd);
}

// strip s: rows [31s, 31s+30] (strip 15: 16 rows). 1024 blocks -> 4/CU, 32 waves/CU.
__global__ __launch_bounds__(512) void box_q9(
    const float* __restrict__ o,     // [NIMG][512][512]
    const float* __restrict__ lab,   // [NIMG][512][512]
    double* __restrict__ acc)        // acc[NIMG]
{
    int bid   = blockIdx.x;
    int img   = bid >> 5;
    int rr    = bid & 31;
    int strip = rr >> 1;
    int xblk  = rr & 1;
    int lane  = threadIdx.x & 63;
    int wid   = threadIdx.x >> 6;

    int c0 = xblk * 256 + wid * 32;
    int cc = min(c0 + lane, CONV - 1);   // clamp: no per-iter masking needed
    int r0 = strip * 31;
    int nrows = min(31, QOUT - r0);      // 31, except strip 15: 16

    const float* op = o   + (size_t)img * CONV * CONV + cc;
    const float* lp = lab + (size_t)img * CONV * CONV + cc;

    bool xvalid = (lane < 32) && (c0 + lane < QOUT);

    float s0 = 0.f, s1 = 0.f, s2 = 0.f, s3 = 0.f;
    {
        int ofs = r0 * CONV;
#pragma unroll 4
        for (int k = 0; k < BS; ++k) {
            float ov = op[ofs], lv = lp[ofs];
            s0 += ov; s1 += lv;
            s2 = fmaf(ov, ov, fmaf(lv, lv, s2));
            s3 = fmaf(ov, lv, s3);
            ofs += CONV;
        }
    }

    float qacc = 0.f;
    int iadd = (r0 + BS) * CONV;
    int isub = r0 * CONV;

#pragma unroll 1
    for (int i = 0; i < 30; ++i) {
        bool more = (i + 1 < nrows);
        float oa = 0.f, la = 0.f, ob = 0.f, lb = 0.f;
        if (more) {
            oa = op[iadd]; la = lp[iadd];
            ob = op[isub]; lb = lp[isub];
        }

        float A0, A1, A2, A3;
        win32pair(s0, s1, lane, A0, A1);
        win32pair(s2, s3, lane, A2, A3);
        if (xvalid && i < nrows) qacc += qval(A0, A1, A2, A3);

        s0 += oa - ob; s1 += la - lb;
        s2 = fmaf(oa, oa, fmaf(la, la, fmaf(ob, -ob, fmaf(lb, -lb, s2))));
        s3 = fmaf(oa, la, fmaf(ob, -lb, s3));
        iadd += CONV; isub += CONV;
    }
    {   // final output (i = nrows-1 for full strips; masked for strip 15)
        float A0, A1, A2, A3;
        win32pair(s0, s1, lane, A0, A1);
        win32pair(s2, s3, lane, A2, A3);
        if (xvalid && nrows == 31) qacc += qval(A0, A1, A2, A3);
    }

    qacc += __shfl_down(qacc, 16, 64);
    qacc += __shfl_down(qacc, 8, 64);
    qacc += __shfl_down(qacc, 4, 64);
    qacc += __shfl_down(qacc, 2, 64);
    qacc += __shfl_down(qacc, 1, 64);
    if (lane == 0) atomicAdd(&acc[img], (double)qacc);
}

__global__ void finalize_kernel(const double* __restrict__ acc, float* __restrict__ out)
{
    double t = 0.0;
    for (int i = 0; i < NIMG; ++i) t += acc[i];
    out[0] = 1.0f - (float)(t / 7403552.0);   // 4*8*481*481
}

extern "C" void kernel_launch(void* const* d_in, const int* in_sizes, int n_in,
                              void* d_out, int out_size, void* d_ws, size_t ws_size,
                              hipStream_t stream)
{
    const float* outputs = (const float*)d_in[0];   // [4,8,552,552]
    const float* labels  = (const float*)d_in[1];   // [4,8,512,512]
    const float* mtf     = (const float*)d_in[2];   // [8,1,41,41]

    double*    acc   = (double*)d_ws;                                   // @0
    float*     o_buf = (float*)((char*)d_ws + 4096);                    // 33.55 MB
    _Float16*  T     = (_Float16*)((char*)d_ws + 4096 + 33554432);      // 20.64 MB
    _Float16*  Atab  = (_Float16*)((char*)d_ws + 4096 + 33554432 + 20643840); // 688 KB

    hipMemsetAsync(d_ws, 0, 512, stream);

    prep_fused<<<TRB + ATB, 256, 0, stream>>>(outputs, T, mtf, Atab);
    conv_mfma16<<<NIMG * 32, 256, 0, stream>>>(T, Atab, o_buf);
    box_q9<<<NIMG * 32, 512, 0, stream>>>(o_buf, labels, acc);
    finalize_kernel<<<1, 1, 0, stream>>>(acc, (float*)d_out);
}

// Round 23
// 116.586 us; speedup vs baseline: 1.3207x; 1.3207x over previous
//
#include <hip/hip_runtime.h>

// Problem constants
#define NBANDS 8
#define BS 32
#define MTF 41
#define IMG 552
#define CONV 512
#define QOUT 481
#define NIMG 32
#define NN 1024.0f
#define KXP 42            // Atab kx entries per band (41 real + 1 zero pad)

// Transposed fp16 input T: [NIMG][TX][TY], zero-padded
#define TX 560
#define TY 576

#define TRB (NIMG * 81)   // transpose blocks: 2592
#define ATB 168           // atab blocks (2 entries each): 336 entries

typedef _Float16 half8 __attribute__((ext_vector_type(8)));
typedef _Float16 half2v __attribute__((ext_vector_type(2)));
typedef float f32x4 __attribute__((ext_vector_type(4)));

// ---------- prep: transpose + fp16 convert, with atab fused as extra blocks ----------
__global__ __launch_bounds__(256) void prep_fused(
    const float* __restrict__ in, _Float16* __restrict__ T,
    const float* __restrict__ w, _Float16* __restrict__ A)
{
    int bid = blockIdx.x;
    if (bid >= TRB) {
        // ---- atab role: 2 (band,kx) entries per block, 128 threads each ----
        int e = (bid - TRB) * 2 + (threadIdx.x >> 7);   // entry = band*KXP + kx
        int band = e / KXP, kx = e % KXP;
        int tt = threadIdx.x & 127;
        int s = tt >> 6, lane = tt & 63;
        int i = lane & 15;
        int kb = 32 * s + ((lane >> 4) << 3);
        const float* wp = w + band * MTF * MTF;
        half8 v;
#pragma unroll
        for (int j = 0; j < 8; ++j) {
            int ky = kb + j - i;
            v[j] = (kx < MTF && ky >= 0 && ky < MTF) ? (_Float16)wp[ky * MTF + kx]
                                                     : (_Float16)0.f;
        }
        *(half8*)&A[(((size_t)(e * 2 + s)) << 9) + lane * 8] = v;
        return;
    }

    // ---- transpose role ----
    __shared__ _Float16 s[64][74];   // pitch 74 halfs = 37 dwords, gcd(37,32)=1
    int img = bid / 81;              // 9x9 tiles of 64
    int t = bid % 81;
    int ty = t / 9, tx2 = t % 9;
    int y0 = ty * 64, x0 = tx2 * 64;
    const float* ip = in + (size_t)img * IMG * IMG;

    if (x0 + 63 < IMG) {
#pragma unroll
        for (int k = 0; k < 4; ++k) {
            int i = k * 256 + threadIdx.x;
            int r = i >> 4, c4 = i & 15;
            int y = y0 + r;
            float4 v = make_float4(0.f, 0.f, 0.f, 0.f);
            if (y < IMG) v = *(const float4*)(ip + (size_t)y * IMG + x0 + c4 * 4);
            s[c4 * 4 + 0][r] = (_Float16)v.x;
            s[c4 * 4 + 1][r] = (_Float16)v.y;
            s[c4 * 4 + 2][r] = (_Float16)v.z;
            s[c4 * 4 + 3][r] = (_Float16)v.w;
        }
    } else {
#pragma unroll
        for (int k = 0; k < 16; ++k) {
            int i = k * 256 + threadIdx.x;
            int r = i >> 6, c = i & 63;
            int y = y0 + r, x = x0 + c;
            float v = (y < IMG && x < IMG) ? ip[(size_t)y * IMG + x] : 0.f;
            s[c][r] = (_Float16)v;
        }
    }
    __syncthreads();
    _Float16* Tp = T + (size_t)img * TX * TY;
    for (int k = 0; k < 2; ++k) {
        int i = k * 256 + threadIdx.x;  // 512 = 64 xi * 8 g
        int xi = i >> 3, g = i & 7;
        int x = x0 + xi;
        if (x < TX) {
            half8 v = *(const half8*)&s[xi][g * 8];
            *(half8*)&Tp[(size_t)x * TY + y0 + g * 8] = v;
        }
    }
}

// ---------- Kernel A: 16x16x32 MFMA conv, wave = 128y x 16x, frag-sharing ----------
#define XP5 105
#define UGS (2 * XP5 * 16)    // byte stride between u-steps: 3360

__global__ __launch_bounds__(256, 4) void conv_mfma16(
    const _Float16* __restrict__ T, const _Float16* __restrict__ Atab,
    float* __restrict__ out)
{
    __shared__ __align__(16) _Float16 sB[22 * XP5 * 8];   // 36960 B
    int bid = blockIdx.x;
    int img = bid >> 5;
    int rr  = bid & 31;
    int y0 = (rr >> 3) << 7;       // 0..384
    int x0 = (rr & 7) << 6;        // 0..448
    int band = img & 7;
    int tid = threadIdx.x;

    const _Float16* Tp = T + (size_t)img * TX * TY;
    for (int e = tid; e < 22 * 104; e += 256) {
        int g = e / 104, x = e - g * 104;
        half8 v = *(const half8*)&Tp[(size_t)(x0 + x) * TY + y0 + g * 8];
        *(half8*)&sB[(size_t)(g * XP5 + x) * 8] = v;
    }
    __syncthreads();

    int l  = tid & 63;
    int wx = tid >> 6;             // 0..3 (16-col x sub-tile)
    int g4 = l >> 4;               // k-quarter -> y-group offset
    int ln = l & 15;

    const half8* Ab = (const half8*)Atab + (size_t)band * KXP * 2 * 64 + l;
    const char* bbase = (const char*)sB + ((size_t)(g4 * XP5 + (wx << 4) + ln) << 4);

    f32x4 acc[8] = {};             // 8 independent MFMA chains

    auto LDA = [&](half8 (&A)[2], int kx) {
        A[0] = Ab[(size_t)(kx * 2) * 64];
        A[1] = Ab[(size_t)(kx * 2 + 1) * 64];
    };
    auto LDB = [&](half8 (&B)[10], int kx) {
        const char* q = bbase + ((size_t)kx << 4);
#pragma unroll
        for (int i = 0; i < 10; ++i) B[i] = *(const half8*)(q + i * UGS);
    };
    auto FMAS = [&](half8 (&A)[2], half8 (&B)[10]) {
#pragma unroll
        for (int t = 0; t < 8; ++t)
            acc[t] = __builtin_amdgcn_mfma_f32_16x16x32_f16(A[0], B[t], acc[t], 0, 0, 0);
#pragma unroll
        for (int t = 0; t < 8; ++t)
            acc[t] = __builtin_amdgcn_mfma_f32_16x16x32_f16(A[1], B[t + 2], acc[t], 0, 0, 0);
    };

    half8 A0[2], A1[2], B[10];
    LDA(A0, 0);
#pragma unroll 1
    for (int kx = 0; kx < 40; kx += 2) {
        LDB(B, kx);
        LDA(A1, kx + 1);
        FMAS(A0, B);
        LDB(B, kx + 1);
        LDA(A0, kx + 2);           // <= 41 (zero-padded entry)
        FMAS(A1, B);
    }
    LDB(B, 40);
    FMAS(A0, B);

    // C/D layout (16x16): col = l&15, row = (l>>4)*4 + r
    float* op = out + (size_t)img * CONV * CONV;
    int col = x0 + (wx << 4) + ln;
    int rb  = y0 + (g4 << 2);
#pragma unroll
    for (int t = 0; t < 8; ++t) {
#pragma unroll
        for (int r = 0; r < 4; ++r)
            op[(size_t)(rb + 16 * t + r) * CONV + col] = acc[t][r];
    }
}

// ---------------- Kernel B: box-sums + Q with packed-f16 scans (R21 + unroll 2) ----------------
template<int C, int RM, int BM, bool BC>
__device__ __forceinline__ int dppadd_h2(int v) {
    int t = __builtin_amdgcn_update_dpp(0, v, C, RM, BM, BC);
    half2v a = __builtin_bit_cast(half2v, v);
    half2v b = __builtin_bit_cast(half2v, t);
    return __builtin_bit_cast(int, a + b);
}

__device__ __forceinline__ int wave_iscan_h2(int v) {
    v = dppadd_h2<0x111, 0xf, 0xf, true >(v);   // row_shr:1
    v = dppadd_h2<0x112, 0xf, 0xf, true >(v);   // row_shr:2
    v = dppadd_h2<0x114, 0xf, 0xf, true >(v);   // row_shr:4
    v = dppadd_h2<0x118, 0xf, 0xf, true >(v);   // row_shr:8
    v = dppadd_h2<0x142, 0xa, 0xf, false>(v);   // row_bcast:15 -> rows 1,3
    v = dppadd_h2<0x143, 0xc, 0xf, false>(v);   // row_bcast:31 -> rows 2,3
    return v;
}

__device__ __forceinline__ void win32pair(float sa, float sb, int lane,
                                          float& wa, float& wb) {
    half2v p = __builtin_bit_cast(half2v, __builtin_amdgcn_cvt_pkrtz(sa, sb));
    int P = wave_iscan_h2(__builtin_bit_cast(int, p));
    int Pg = __shfl(P, lane + 31, 64);
    half2v w = __builtin_bit_cast(half2v, Pg) - __builtin_bit_cast(half2v, P) + p;
    wa = (float)w[0];
    wb = (float)w[1];
}

__device__ __forceinline__ float qval(float A0, float A1, float A2, float A3) {
    float mul = A0 * A1;
    float sq  = fmaf(A0, A0, A1 * A1);
    float num = 4.f * fmaf(NN, A3, -mul) * mul;
    float dt  = fmaf(NN, A2, -sq);
    float den = dt * sq;
    bool  c1  = (dt == 0.f) && (sq != 0.f);
    float nn = num, dd = den;
    if (den == 0.f) { nn = c1 ? 2.f * mul : 1.f; dd = c1 ? sq : 1.f; }
    return nn * __builtin_amdgcn_rcpf(dd);
}

#define B_OFF (31 * CONV)

__global__ __launch_bounds__(512) void box_q4(
    const float* __restrict__ o,     // [NIMG][512][512]
    const float* __restrict__ lab,   // [NIMG][512][512]
    double* __restrict__ acc)        // acc[NIMG]
{
    int bid  = blockIdx.x;
    int img  = bid >> 4;
    int rr   = bid & 15;
    int pair = rr >> 1;
    int xblk = rr & 1;
    int lane = threadIdx.x & 63;
    int wid  = threadIdx.x >> 6;

    int c0 = xblk * 256 + wid * 32;
    int cc = min(c0 + lane, CONV - 1);   // clamp: no per-iter masking needed
    int r0A = pair * 62;

    const float* op = o   + (size_t)img * CONV * CONV + cc;
    const float* lp = lab + (size_t)img * CONV * CONV + cc;

    bool xvalid = (lane < 32) && (c0 + lane < QOUT);

    float sA0=0,sA1=0,sA2=0,sA3=0, sB0=0,sB1=0,sB2=0,sB3=0;
    {
        int ofs = r0A * CONV;
#pragma unroll 4
        for (int k = 0; k < BS; ++k) {
            float ov = op[ofs],         lv = lp[ofs];
            float ow = op[ofs + B_OFF], lw = lp[ofs + B_OFF];
            sA0 += ov; sA1 += lv;
            sA2 = fmaf(ov, ov, fmaf(lv, lv, sA2)); sA3 = fmaf(ov, lv, sA3);
            sB0 += ow; sB1 += lw;
            sB2 = fmaf(ow, ow, fmaf(lw, lw, sB2)); sB3 = fmaf(ow, lw, sB3);
            ofs += CONV;
        }
    }

    float qacc = 0.f;
    int iadd = (r0A + BS) * CONV;
    int isub = r0A * CONV;

    if (pair < 7) {
        // unroll 2: expose cross-iteration scan ILP (recurrence only via s*)
#pragma unroll 2
        for (int i = 0; i < 30; ++i) {
            float oa = op[iadd],         la2 = lp[iadd];
            float ob = op[isub],         lb  = lp[isub];
            float oc = op[iadd + B_OFF], lc  = lp[iadd + B_OFF];
            float od = op[isub + B_OFF], ld  = lp[isub + B_OFF];

            float A0, A1, A2, A3, B0, B1, B2, B3;
            win32pair(sA0, sA1, lane, A0, A1);
            win32pair(sA2, sA3, lane, A2, A3);
            win32pair(sB0, sB1, lane, B0, B1);
            win32pair(sB2, sB3, lane, B2, B3);
            if (xvalid) {
                qacc += qval(A0, A1, A2, A3);
                qacc += qval(B0, B1, B2, B3);
            }

            sA0 += oa - ob; sA1 += la2 - lb;
            sA2 = fmaf(oa, oa, fmaf(la2, la2, fmaf(ob, -ob, fmaf(lb, -lb, sA2))));
            sA3 = fmaf(oa, la2, fmaf(ob, -lb, sA3));
            sB0 += oc - od; sB1 += lc - ld;
            sB2 = fmaf(oc, oc, fmaf(lc, lc, fmaf(od, -od, fmaf(ld, -ld, sB2))));
            sB3 = fmaf(oc, lc, fmaf(od, -ld, sB3));
            iadd += CONV; isub += CONV;
        }
        {   // final outputs (i = 30), no slide
            float A0, A1, A2, A3, B0, B1, B2, B3;
            win32pair(sA0, sA1, lane, A0, A1);
            win32pair(sA2, sA3, lane, A2, A3);
            win32pair(sB0, sB1, lane, B0, B1);
            win32pair(sB2, sB3, lane, B2, B3);
            if (xvalid) {
                qacc += qval(A0, A1, A2, A3);
                qacc += qval(B0, B1, B2, B3);
            }
        }
    } else {
        // pair 7: chain A 31 outputs, chain B 16 outputs (rows 465..480)
#pragma unroll 1
        for (int i = 0; i < 31; ++i) {
            bool mA = (i < 30), mB = (i + 1 < 16);
            float oa=0,la2=0,ob=0,lb=0, oc=0,lc=0,od=0,ld=0;
            if (mA) {
                oa = op[iadd]; la2 = lp[iadd];
                ob = op[isub]; lb  = lp[isub];
            }
            if (mB) {
                oc = op[iadd + B_OFF]; lc = lp[iadd + B_OFF];
                od = op[isub + B_OFF]; ld = lp[isub + B_OFF];
            }

            {
                float A0, A1, A2, A3;
                win32pair(sA0, sA1, lane, A0, A1);
                win32pair(sA2, sA3, lane, A2, A3);
                if (xvalid) qacc += qval(A0, A1, A2, A3);
            }
            if (i < 16) {
                float B0, B1, B2, B3;
                win32pair(sB0, sB1, lane, B0, B1);
                win32pair(sB2, sB3, lane, B2, B3);
                if (xvalid) qacc += qval(B0, B1, B2, B3);
            }

            sA0 += oa - ob; sA1 += la2 - lb;
            sA2 = fmaf(oa, oa, fmaf(la2, la2, fmaf(ob, -ob, fmaf(lb, -lb, sA2))));
            sA3 = fmaf(oa, la2, fmaf(ob, -lb, sA3));
            sB0 += oc - od; sB1 += lc - ld;
            sB2 = fmaf(oc, oc, fmaf(lc, lc, fmaf(od, -od, fmaf(ld, -ld, sB2))));
            sB3 = fmaf(oc, lc, fmaf(od, -ld, sB3));
            iadd += CONV; isub += CONV;
        }
    }

    qacc += __shfl_down(qacc, 16, 64);
    qacc += __shfl_down(qacc, 8, 64);
    qacc += __shfl_down(qacc, 4, 64);
    qacc += __shfl_down(qacc, 2, 64);
    qacc += __shfl_down(qacc, 1, 64);
    if (lane == 0) atomicAdd(&acc[img], (double)qacc);
}

__global__ void finalize_kernel(const double* __restrict__ acc, float* __restrict__ out)
{
    double t = 0.0;
    for (int i = 0; i < NIMG; ++i) t += acc[i];
    out[0] = 1.0f - (float)(t / 7403552.0);   // 4*8*481*481
}

extern "C" void kernel_launch(void* const* d_in, const int* in_sizes, int n_in,
                              void* d_out, int out_size, void* d_ws, size_t ws_size,
                              hipStream_t stream)
{
    const float* outputs = (const float*)d_in[0];   // [4,8,552,552]
    const float* labels  = (const float*)d_in[1];   // [4,8,512,512]
    const float* mtf     = (const float*)d_in[2];   // [8,1,41,41]

    double*    acc   = (double*)d_ws;                                   // @0
    float*     o_buf = (float*)((char*)d_ws + 4096);                    // 33.55 MB
    _Float16*  T     = (_Float16*)((char*)d_ws + 4096 + 33554432);      // 20.64 MB
    _Float16*  Atab  = (_Float16*)((char*)d_ws + 4096 + 33554432 + 20643840); // 688 KB

    hipMemsetAsync(d_ws, 0, 512, stream);

    prep_fused<<<TRB + ATB, 256, 0, stream>>>(outputs, T, mtf, Atab);
    conv_mfma16<<<NIMG * 32, 256, 0, stream>>>(T, Atab, o_buf);
    box_q4<<<NIMG * 16, 512, 0, stream>>>(o_buf, labels, acc);
    finalize_kernel<<<1, 1, 0, stream>>>(acc, (float*)d_out);
}